// Round 19
// baseline (1325.647 us; speedup 1.0000x reference)
//
#include <hip/hip_runtime.h>
#include <stdint.h>

#define N_NODES 4096
#define NGRAPH 8
#define NPTS 512
#define KNN 64
#define EPSN 1e-5f
#define FBLK 512

typedef _Float16 f16x8 __attribute__((ext_vector_type(8)));
typedef float f32x4 __attribute__((ext_vector_type(4)));
typedef unsigned long long u64;

__device__ __forceinline__ unsigned short f2h(float f) {
    _Float16 h = (_Float16)f;   // RNE, v_cvt_f16_f32
    union { _Float16 h; unsigned short u; } cv; cv.h = h;
    return cv.u;
}

// 16-col blocked layout (for 16x16x32 MFMA)
__device__ __forceinline__ void w2cv(const float* __restrict__ src, unsigned short* __restrict__ dst,
                                     int off, int lg2c) {
    int C = 1 << lg2c;
    int k = off >> lg2c, n = off & (C - 1);
    int d = ((n >> 4) * (C / 32) + (k >> 5)) * 512 + ((k >> 3) & 3) * 128 + (n & 15) * 8 + (k & 7);
    dst[d] = f2h(src[off]);
}

// ---- grid barrier: monotonic generation counter (valid across graph replays) ----
__device__ __forceinline__ void gridbar(u64* cnt) {
    __syncthreads();
    if (threadIdx.x == 0) {
        __threadfence();
        u64 old = __hip_atomic_fetch_add(cnt, 1ull, __ATOMIC_ACQ_REL, __HIP_MEMORY_SCOPE_AGENT);
        u64 target = (old / FBLK + 1) * FBLK;
        while (__hip_atomic_load(cnt, __ATOMIC_ACQUIRE, __HIP_MEMORY_SCOPE_AGENT) < target)
            __builtin_amdgcn_s_sleep(2);
        __threadfence();
    }
    __syncthreads();
}

// ---------------- setup: w2 conversions + stat-zero + gn1 stats + kNN, one dispatch ----------------
__global__ __launch_bounds__(64) void setup_kernel(const float* __restrict__ pos, int* __restrict__ knn_out,
                                                   const float* __restrict__ wa, const float* __restrict__ wb,
                                                   const float* __restrict__ wc, const float* __restrict__ wd,
                                                   const float* __restrict__ we,
                                                   unsigned short* __restrict__ oa, unsigned short* __restrict__ ob,
                                                   unsigned short* __restrict__ oc, unsigned short* __restrict__ od,
                                                   unsigned short* __restrict__ oe,
                                                   float* __restrict__ statz,
                                                   const float* __restrict__ ms1, const float* __restrict__ gw1,
                                                   float* __restrict__ Aa, float* __restrict__ Sa) {
#pragma clang fp contract(off)
    __shared__ float px[NPTS], py[NPTS], pz[NPTS];
    __shared__ u64 keys[NPTS];
    int bid = blockIdx.x;
    int tid = threadIdx.x;   // 0..63
    int gidx = bid * 64 + tid;           // 0..262143
    for (int idx = gidx; idx < 40960; idx += 262144) statz[idx] = 0.f;
    for (int idx = gidx; idx < 610304; idx += 262144) {
        if (idx < 4096)        w2cv(wa, oa, idx, 6);
        else if (idx < 20480)  w2cv(wb, ob, idx - 4096, 7);
        else if (idx < 86016)  w2cv(wc, oc, idx - 20480, 8);
        else if (idx < 348160) w2cv(wd, od, idx - 86016, 9);
        else                   w2cv(we, oe, idx - 348160, 9);
    }
    if (bid < 24) {   // gn1 stats: 24 (graph,channel) wave-jobs
        int g = bid / 3, ch = bid - g * 3;
        float s1 = 0.f, s2 = 0.f;
        for (int n = tid; n < NPTS; n += 64) {
            float v = pos[(g * NPTS + n) * 3 + ch];
            s1 += v; s2 += v * v;
        }
        #pragma unroll
        for (int off = 32; off; off >>= 1) { s1 += __shfl_xor(s1, off); s2 += __shfl_xor(s2, off); }
        if (tid == 0) {
            float mean = s1 * (1.f / NPTS);
            float av = mean * ms1[ch];
            float var = s2 * (1.f / NPTS) - 2.f * av * mean + av * av;
            Aa[g * 3 + ch] = av;
            Sa[g * 3 + ch] = gw1[ch] / sqrtf(var + EPSN);
        }
    }
    // ---- kNN: 1-wave bitonic sort of this dst point's 512 keys ----
    int b = bid >> 9;
    int il = bid & (NPTS - 1);
    for (int n = tid; n < NPTS; n += 64) {
        int base = (b * NPTS + n) * 3;
        px[n] = pos[base]; py[n] = pos[base + 1]; pz[n] = pos[base + 2];
    }
    __syncthreads();
    float xi = px[il], yi = py[il], zi = pz[il];
    for (int n = tid; n < NPTS; n += 64) {
        float dx = px[n] - xi, dy = py[n] - yi, dz = pz[n] - zi;
        float d2 = dx * dx;
        d2 = d2 + dy * dy;
        d2 = d2 + dz * dz;
        keys[n] = (((u64)__float_as_uint(d2)) << 32) | (unsigned)n;
    }
    __syncthreads();
    for (int k2 = 2; k2 <= NPTS; k2 <<= 1) {
        for (int j = k2 >> 1; j > 0; j >>= 1) {
            #pragma unroll 4
            for (int p = 0; p < 4; ++p) {
                int pid = tid + p * 64;
                int t = ((pid & ~(j - 1)) << 1) | (pid & (j - 1));
                int ixj = t | j;
                u64 a = keys[t], c = keys[ixj];
                bool up = ((t & k2) == 0);
                if ((a > c) == up) { keys[t] = c; keys[ixj] = a; }
            }
            __syncthreads();
        }
    }
    int j0 = (int)(keys[tid] & 0xffffffffu);
    knn_out[(size_t)(b * NPTS + il) * KNN + tid] = b * NPTS + j0;
}

// ---------------- Per-node MLP1 with fused GraphNorm apply on input ----------------
template<int CIN, int C, int RELU, int RAW>
__global__ __launch_bounds__(C) void node_kernel(const float* __restrict__ y, const float* __restrict__ pos,
                                                 const float* __restrict__ p1, const float* __restrict__ p2,
                                                 const float* __restrict__ ms, const float* __restrict__ gw,
                                                 const float* __restrict__ bnp,
                                                 const float* __restrict__ w1, const float* __restrict__ b1,
                                                 float* __restrict__ U, float* __restrict__ P) {
    constexpr int ROWS = 16;
    constexpr int KC = 64;
    constexpr int LDH = KC + 4;
    __shared__ float hs[ROWS][LDH];   // 4352 B
    __shared__ float As_[CIN > 0 ? CIN : 1], Ss_[CIN > 0 ? CIN : 1];
    const int c = threadIdx.x;
    const int n0 = blockIdx.x * ROWS;
    const int b = n0 >> 9;            // all 16 rows in one graph
    if (RAW) {
        for (int ch = c; ch < CIN; ch += C) {
            float s1 = p1[b * CIN + ch], s2 = p2[b * CIN + ch];
            float mean = s1 * (1.f / NPTS);
            float a = mean * ms[ch];
            float var = s2 * (1.f / NPTS) - 2.f * a * mean + a * a;
            As_[ch] = a;
            Ss_[ch] = gw[ch] / sqrtf(var + EPSN);
        }
    }
    float acc[ROWS];
    #pragma unroll
    for (int r = 0; r < ROWS; ++r) acc[r] = 0.f;
    constexpr int NCHUNK = (CIN + KC - 1) / KC;
    #pragma unroll 1
    for (int s = 0; s < NCHUNK; ++s) {
        const int k0 = s * KC;
        const int kc = (CIN - k0 < KC) ? (CIN - k0) : KC;
        __syncthreads();
        for (int idx = c; idx < ROWS * kc; idx += C) {
            int r = idx / kc, k = idx - r * kc;
            int ch = k0 + k;
            float a = RAW ? As_[ch] : p1[b * CIN + ch];
            float sf = RAW ? Ss_[ch] : p2[b * CIN + ch];
            float v = (y[(size_t)(n0 + r) * CIN + ch] - a) * sf + bnp[ch];
            if (RELU) v = fmaxf(v, 0.f);
            hs[r][k] = v;
        }
        __syncthreads();
        int k = 0;
        for (; k + 4 <= kc; k += 4) {
            float w0 = w1[(size_t)(k0 + k) * C + c];
            float w1v = w1[(size_t)(k0 + k + 1) * C + c];
            float w2v = w1[(size_t)(k0 + k + 2) * C + c];
            float w3v = w1[(size_t)(k0 + k + 3) * C + c];
            #pragma unroll
            for (int r = 0; r < ROWS; ++r) {
                f32x4 hv = *(const f32x4*)&hs[r][k];
                acc[r] = fmaf(hv[0], w0, acc[r]);
                acc[r] = fmaf(hv[1], w1v, acc[r]);
                acc[r] = fmaf(hv[2], w2v, acc[r]);
                acc[r] = fmaf(hv[3], w3v, acc[r]);
            }
        }
        for (; k < kc; ++k) {
            float wv = w1[(size_t)(k0 + k) * C + c];
            #pragma unroll
            for (int r = 0; r < ROWS; ++r)
                acc[r] = fmaf(hs[r][k], wv, acc[r]);
        }
    }
    float pacc[ROWS];
    #pragma unroll
    for (int r = 0; r < ROWS; ++r) pacc[r] = 0.f;
    #pragma unroll
    for (int e = 0; e < 3; ++e) {
        float wv = w1[(size_t)(CIN + e) * C + c];
        #pragma unroll
        for (int r = 0; r < ROWS; ++r)
            pacc[r] = fmaf(pos[(n0 + r) * 3 + e], wv, pacc[r]);
    }
    float bv = b1[c];
    #pragma unroll
    for (int r = 0; r < ROWS; ++r) {
        U[(size_t)(n0 + r) * C + c] = acc[r] + pacc[r] + bv;
        P[(size_t)(n0 + r) * C + c] = pacc[r];
    }
}

// ---------------- Edge MLP2 + scatter-max (R18 shape; P-row LDS) + atomic stats ----------------
template<int C, int W>
__global__ __launch_bounds__(W * 64, 4) void edge_kernel(const float* __restrict__ U, const float* __restrict__ P,
                                                         const int* __restrict__ knn, const unsigned short* __restrict__ w2t,
                                                         const float* __restrict__ b2, float* __restrict__ Y,
                                                         float* __restrict__ sum1, float* __restrict__ sum2) {
    constexpr int NCT = C / (W * 16);
    constexpr int EPT = 32 / W;
    constexpr int S = C / 32;
    constexpr int LD = 40;
    __shared__ unsigned short Tb[2][64 * LD];
    __shared__ int jn[64];
    __shared__ float Pr[C];
    const int bid = blockIdx.x;
    const int i = ((bid & 7) << 9) | (bid >> 3);
    const int tid = threadIdx.x;
    const int wave = tid >> 6, lane = tid & 63, m = lane & 15, quad = lane >> 4;
    const int cw = wave * (NCT * 16);
    if (tid < 64) jn[tid] = knn[(size_t)i * KNN + tid];
    for (int idx = tid; idx < C; idx += W * 64) Pr[idx] = P[(size_t)i * C + idx];
    f32x4 acc[4][NCT];
    f32x4 zero = {0.f, 0.f, 0.f, 0.f};
    #pragma unroll
    for (int rt = 0; rt < 4; ++rt)
        #pragma unroll
        for (int ct = 0; ct < NCT; ++ct)
            acc[rt][ct] = zero;
    const int rr = tid / W;
    const int c0 = (tid % W) * EPT;
    __syncthreads();
    const float* upr = U + (size_t)jn[rr] * C + c0;
    float4 uf[EPT / 4];
    #pragma unroll
    for (int g = 0; g < EPT / 4; ++g)
        uf[g] = *(const float4*)(upr + g * 4);
    #pragma unroll 2
    for (int s = 0; s < S; ++s) {
        unsigned short* tb = Tb[s & 1];
        if constexpr (EPT == 8) {
            float4 p0 = *(const float4*)&Pr[s * 32 + c0];
            float4 p1 = *(const float4*)&Pr[s * 32 + c0 + 4];
            uint4 pk;
            pk.x = (unsigned)f2h(fmaxf(uf[0].x - p0.x, 0.f)) | ((unsigned)f2h(fmaxf(uf[0].y - p0.y, 0.f)) << 16);
            pk.y = (unsigned)f2h(fmaxf(uf[0].z - p0.z, 0.f)) | ((unsigned)f2h(fmaxf(uf[0].w - p0.w, 0.f)) << 16);
            pk.z = (unsigned)f2h(fmaxf(uf[1].x - p1.x, 0.f)) | ((unsigned)f2h(fmaxf(uf[1].y - p1.y, 0.f)) << 16);
            pk.w = (unsigned)f2h(fmaxf(uf[1].z - p1.z, 0.f)) | ((unsigned)f2h(fmaxf(uf[1].w - p1.w, 0.f)) << 16);
            *(uint4*)&tb[rr * LD + c0] = pk;
        } else {
            float4 p0 = *(const float4*)&Pr[s * 32 + c0];
            uint2 pk;
            pk.x = (unsigned)f2h(fmaxf(uf[0].x - p0.x, 0.f)) | ((unsigned)f2h(fmaxf(uf[0].y - p0.y, 0.f)) << 16);
            pk.y = (unsigned)f2h(fmaxf(uf[0].z - p0.z, 0.f)) | ((unsigned)f2h(fmaxf(uf[0].w - p0.w, 0.f)) << 16);
            *(uint2*)&tb[rr * LD + c0] = pk;
        }
        if (s + 1 < S) {
            #pragma unroll
            for (int g = 0; g < EPT / 4; ++g)
                uf[g] = *(const float4*)(upr + (s + 1) * 32 + g * 4);
        }
        __syncthreads();
        f16x8 a[4];
        #pragma unroll
        for (int rt = 0; rt < 4; ++rt)
            a[rt] = *(const f16x8*)&tb[(rt * 16 + m) * LD + quad * 8];
        #pragma unroll
        for (int ct = 0; ct < NCT; ++ct) {
            const f16x8 bb = *(const f16x8*)(w2t +
                (size_t)(((cw >> 4) + ct) * S + s) * 512 + quad * 128 + m * 8);
            #pragma unroll
            for (int rt = 0; rt < 4; ++rt)
                acc[rt][ct] = __builtin_amdgcn_mfma_f32_16x16x32_f16(a[rt], bb, acc[rt][ct], 0, 0, 0);
        }
    }
    const int gb = i >> 9;
    #pragma unroll
    for (int ct = 0; ct < NCT; ++ct) {
        float vmax = -3.4e38f;
        #pragma unroll
        for (int rt = 0; rt < 4; ++rt) {
            vmax = fmaxf(vmax, acc[rt][ct][0]);
            vmax = fmaxf(vmax, acc[rt][ct][1]);
            vmax = fmaxf(vmax, acc[rt][ct][2]);
            vmax = fmaxf(vmax, acc[rt][ct][3]);
        }
        vmax = fmaxf(vmax, __shfl_xor(vmax, 16));
        vmax = fmaxf(vmax, __shfl_xor(vmax, 32));
        if (quad == 0) {
            int col = cw + ct * 16 + m;
            float val = vmax + b2[col];
            Y[(size_t)i * C + col] = val;
            atomicAdd(&sum1[gb * C + col], val);
            atomicAdd(&sum2[gb * C + col], val * val);
        }
    }
}

// ---------------- Fused node+edge for C=512 layers: persistent 512 blocks + grid barrier ----------------
template<int CIN>
__global__ __launch_bounds__(512, 4) void fused_kernel(const float* __restrict__ y, const float* __restrict__ pos,
                                                       const float* __restrict__ p1, const float* __restrict__ p2,
                                                       const float* __restrict__ ms, const float* __restrict__ gw,
                                                       const float* __restrict__ bnp,
                                                       const float* __restrict__ w1, const float* __restrict__ b1,
                                                       float* __restrict__ U, float* __restrict__ P,
                                                       const int* __restrict__ knn, const unsigned short* __restrict__ w2t,
                                                       const float* __restrict__ b2, float* __restrict__ Y,
                                                       float* __restrict__ sum1, float* __restrict__ sum2,
                                                       u64* __restrict__ bar) {
    constexpr int C = 512;
    constexpr int ROWS = 16;
    constexpr int KC = 64;
    constexpr int LDH = KC + 4;
    constexpr int NCT = 4, S = 16, LD = 40;   // edge shape (W=8)
    __shared__ union {
        struct { float hs[ROWS][LDH]; float As_[512], Ss_[512]; } n;
        struct { unsigned short Tb[2][64 * LD]; int jn[64]; float Pr[C]; } e;
    } sm;
    const int bid = blockIdx.x;
    const int tid = threadIdx.x;

    // ---- node phase (blocks 0..255) ----
    if (bid < N_NODES / ROWS) {
        const int c = tid;
        const int n0 = bid * ROWS;
        const int b = n0 >> 9;
        for (int ch = c; ch < CIN; ch += 512) {
            float s1 = p1[b * CIN + ch], s2 = p2[b * CIN + ch];
            float mean = s1 * (1.f / NPTS);
            float a = mean * ms[ch];
            float var = s2 * (1.f / NPTS) - 2.f * a * mean + a * a;
            sm.n.As_[ch] = a;
            sm.n.Ss_[ch] = gw[ch] / sqrtf(var + EPSN);
        }
        float acc[ROWS];
        #pragma unroll
        for (int r = 0; r < ROWS; ++r) acc[r] = 0.f;
        constexpr int NCHUNK = (CIN + KC - 1) / KC;
        #pragma unroll 1
        for (int s = 0; s < NCHUNK; ++s) {
            const int k0 = s * KC;
            const int kc = (CIN - k0 < KC) ? (CIN - k0) : KC;
            __syncthreads();
            for (int idx = c; idx < ROWS * kc; idx += 512) {
                int r = idx / kc, k = idx - r * kc;
                int ch = k0 + k;
                float v = (y[(size_t)(n0 + r) * CIN + ch] - sm.n.As_[ch]) * sm.n.Ss_[ch] + bnp[ch];
                sm.n.hs[r][k] = fmaxf(v, 0.f);
            }
            __syncthreads();
            int k = 0;
            for (; k + 4 <= kc; k += 4) {
                float w0 = w1[(size_t)(k0 + k) * C + c];
                float w1v = w1[(size_t)(k0 + k + 1) * C + c];
                float w2v = w1[(size_t)(k0 + k + 2) * C + c];
                float w3v = w1[(size_t)(k0 + k + 3) * C + c];
                #pragma unroll
                for (int r = 0; r < ROWS; ++r) {
                    f32x4 hv = *(const f32x4*)&sm.n.hs[r][k];
                    acc[r] = fmaf(hv[0], w0, acc[r]);
                    acc[r] = fmaf(hv[1], w1v, acc[r]);
                    acc[r] = fmaf(hv[2], w2v, acc[r]);
                    acc[r] = fmaf(hv[3], w3v, acc[r]);
                }
            }
        }
        float pacc[ROWS];
        #pragma unroll
        for (int r = 0; r < ROWS; ++r) pacc[r] = 0.f;
        #pragma unroll
        for (int e = 0; e < 3; ++e) {
            float wv = w1[(size_t)(CIN + e) * C + c];
            #pragma unroll
            for (int r = 0; r < ROWS; ++r)
                pacc[r] = fmaf(pos[(n0 + r) * 3 + e], wv, pacc[r]);
        }
        float bv = b1[c];
        #pragma unroll
        for (int r = 0; r < ROWS; ++r) {
            U[(size_t)(n0 + r) * C + c] = acc[r] + pacc[r] + bv;
            P[(size_t)(n0 + r) * C + c] = pacc[r];
        }
    }
    gridbar(bar);

    // ---- edge phase: 8 virtual nodes per block ----
    const int wave = tid >> 6, lane = tid & 63, m = lane & 15, quad = lane >> 4;
    const int cw = wave * (NCT * 16);
    const int rr = tid >> 3;
    const int c0 = (tid & 7) * 4;        // EPT=4
    #pragma unroll 1
    for (int v = bid; v < N_NODES; v += FBLK) {
        const int i = ((v & 7) << 9) | (v >> 3);
        if (tid < 64) sm.e.jn[tid] = knn[(size_t)i * KNN + tid];
        for (int idx = tid; idx < C; idx += 512) sm.e.Pr[idx] = P[(size_t)i * C + idx];
        f32x4 acc[4][NCT];
        f32x4 zero = {0.f, 0.f, 0.f, 0.f};
        #pragma unroll
        for (int rt = 0; rt < 4; ++rt)
            #pragma unroll
            for (int ct = 0; ct < NCT; ++ct)
                acc[rt][ct] = zero;
        __syncthreads();
        const float* upr = U + (size_t)sm.e.jn[rr] * C + c0;
        float4 uf = *(const float4*)upr;
        #pragma unroll 2
        for (int s = 0; s < S; ++s) {
            unsigned short* tb = sm.e.Tb[s & 1];
            float4 p0 = *(const float4*)&sm.e.Pr[s * 32 + c0];
            uint2 pk;
            pk.x = (unsigned)f2h(fmaxf(uf.x - p0.x, 0.f)) | ((unsigned)f2h(fmaxf(uf.y - p0.y, 0.f)) << 16);
            pk.y = (unsigned)f2h(fmaxf(uf.z - p0.z, 0.f)) | ((unsigned)f2h(fmaxf(uf.w - p0.w, 0.f)) << 16);
            *(uint2*)&tb[rr * LD + c0] = pk;
            if (s + 1 < S)
                uf = *(const float4*)(upr + (s + 1) * 32);
            __syncthreads();
            f16x8 a[4];
            #pragma unroll
            for (int rt = 0; rt < 4; ++rt)
                a[rt] = *(const f16x8*)&tb[(rt * 16 + m) * LD + quad * 8];
            #pragma unroll
            for (int ct = 0; ct < NCT; ++ct) {
                const f16x8 bb = *(const f16x8*)(w2t +
                    (size_t)(((cw >> 4) + ct) * S + s) * 512 + quad * 128 + m * 8);
                #pragma unroll
                for (int rt = 0; rt < 4; ++rt)
                    acc[rt][ct] = __builtin_amdgcn_mfma_f32_16x16x32_f16(a[rt], bb, acc[rt][ct], 0, 0, 0);
            }
        }
        const int gb = i >> 9;
        #pragma unroll
        for (int ct = 0; ct < NCT; ++ct) {
            float vmax = -3.4e38f;
            #pragma unroll
            for (int rt = 0; rt < 4; ++rt) {
                vmax = fmaxf(vmax, acc[rt][ct][0]);
                vmax = fmaxf(vmax, acc[rt][ct][1]);
                vmax = fmaxf(vmax, acc[rt][ct][2]);
                vmax = fmaxf(vmax, acc[rt][ct][3]);
            }
            vmax = fmaxf(vmax, __shfl_xor(vmax, 16));
            vmax = fmaxf(vmax, __shfl_xor(vmax, 32));
            if (quad == 0) {
                int col = cw + ct * 16 + m;
                float val = vmax + b2[col];
                Y[(size_t)i * C + col] = val;
                atomicAdd(&sum1[gb * C + col], val);
                atomicAdd(&sum2[gb * C + col], val * val);
            }
        }
        __syncthreads();   // Tb/Pr WAR before next v's prologue writes
    }
}

// ---------------- Classifier with fused gn6 (stats from atomic sums) ----------------
__global__ __launch_bounds__(256) void cls_kernel(const float* __restrict__ y, const float* __restrict__ sum1,
                                                  const float* __restrict__ sum2, const float* __restrict__ ms,
                                                  const float* __restrict__ gw, const float* __restrict__ gnb,
                                                  const float* __restrict__ w, const float* __restrict__ bias,
                                                  float* __restrict__ out) {
    __shared__ float wl[512 * 14];
    __shared__ _Float16 hn[16][520];
    __shared__ float As[512], Ss[512];
    int tid = threadIdx.x;
    int n0 = blockIdx.x * 16;
    int b = n0 >> 9;
    for (int ch = tid; ch < 512; ch += 256) {
        float s1 = sum1[b * 512 + ch], s2 = sum2[b * 512 + ch];
        float mean = s1 * (1.f / NPTS);
        float a = mean * ms[ch];
        float var = s2 * (1.f / NPTS) - 2.f * a * mean + a * a;
        As[ch] = a;
        Ss[ch] = gw[ch] / sqrtf(var + EPSN);
    }
    for (int idx = tid; idx < 512 * 14; idx += 256) wl[idx] = w[idx];
    __syncthreads();
    for (int idx = tid; idx < 16 * 512; idx += 256) {
        int r = idx >> 9, k = idx & 511;
        float v = (y[(size_t)(n0 + r) * 512 + k] - As[k]) * Ss[k] + gnb[k];
        hn[r][k] = (_Float16)fmaxf(v, 0.f);
    }
    __syncthreads();
    if (tid < 224) {
        int nl = tid / 14, c = tid - nl * 14;
        float acc = bias[c];
        for (int k = 0; k < 512; ++k)
            acc += (float)hn[nl][k] * wl[k * 14 + c];
        out[(size_t)(n0 + nl) * 14 + c] = acc;
    }
}

extern "C" void kernel_launch(void* const* d_in, const int* in_sizes, int n_in,
                              void* d_out, int out_size, void* d_ws, size_t ws_size,
                              hipStream_t stream) {
    const float* pos = (const float*)d_in[0];
    const float* gnw[6]; const float* gnb[6]; const float* gnms[6];
    for (int i = 0; i < 6; ++i) {
        gnw[i]  = (const float*)d_in[2 + 3 * i];
        gnb[i]  = (const float*)d_in[3 + 3 * i];
        gnms[i] = (const float*)d_in[4 + 3 * i];
    }
    const float* cw1[5]; const float* cb1[5]; const float* cw2[5]; const float* cb2[5];
    for (int i = 0; i < 5; ++i) {
        cw1[i] = (const float*)d_in[20 + 4 * i];
        cb1[i] = (const float*)d_in[21 + 4 * i];
        cw2[i] = (const float*)d_in[22 + 4 * i];
        cb2[i] = (const float*)d_in[23 + 4 * i];
    }
    const float* clsw = (const float*)d_in[40];
    const float* clsb = (const float*)d_in[41];
    float* out = (float*)d_out;

    char* ws = (char*)d_ws;
    int* knn             = (int*)(ws + 0);                 // 1 MB
    float* U             = (float*)(ws + 1048576);         // 8 MB
    float* P             = (float*)(ws + 9437184);         // 8 MB
    float* y             = (float*)(ws + 26214400);        // 8 MB
    float* Aa            = (float*)(ws + 34603008);        // 16 KB
    float* Sa            = (float*)(ws + 34619392);        // 16 KB
    unsigned short* w2t0 = (unsigned short*)(ws + 34635776);  // 8 KB
    unsigned short* w2t1 = (unsigned short*)(ws + 34643968);  // 32 KB
    unsigned short* w2t2 = (unsigned short*)(ws + 34676736);  // 128 KB
    unsigned short* w2t3 = (unsigned short*)(ws + 34807808);  // 512 KB
    unsigned short* w2t4 = (unsigned short*)(ws + 35332096);  // 512 KB
    float* acc           = (float*)(ws + 35856384);           // 160 KB: 5 x (4096+4096) floats
    u64* bar             = (u64*)(ws + 36020224);             // 64 B barrier counter
    float* s1l[5]; float* s2l[5];
    for (int l = 0; l < 5; ++l) { s1l[l] = acc + l * 8192; s2l[l] = s1l[l] + 4096; }

    hipMemsetAsync((void*)bar, 0, 64, stream);

    // setup: w2 conversions + stat-zero + gn1 stats + kNN
    setup_kernel<<<N_NODES, 64, 0, stream>>>(pos, knn, cw2[0], cw2[1], cw2[2], cw2[3], cw2[4],
                                             w2t0, w2t1, w2t2, w2t3, w2t4, acc,
                                             gnms[0], gnw[0], Aa, Sa);

    // Layer 1 (gn1 apply fused into node1, no relu)
    node_kernel<3, 64, 0, 0><<<N_NODES / 16, 64, 0, stream>>>(pos, pos, Aa, Sa, gnms[0], gnw[0], gnb[0], cw1[0], cb1[0], U, P);
    edge_kernel<64, 4><<<N_NODES, 256, 0, stream>>>(U, P, knn, w2t0, cb2[0], y, s1l[0], s2l[0]);

    // Layer 2 (stats from L1 edge atomics)
    node_kernel<64, 128, 1, 1><<<N_NODES / 16, 128, 0, stream>>>(y, pos, s1l[0], s2l[0], gnms[1], gnw[1], gnb[1], cw1[1], cb1[1], U, P);
    edge_kernel<128, 8><<<N_NODES, 512, 0, stream>>>(U, P, knn, w2t1, cb2[1], y, s1l[1], s2l[1]);

    // Layer 3
    node_kernel<128, 256, 1, 1><<<N_NODES / 16, 256, 0, stream>>>(y, pos, s1l[1], s2l[1], gnms[2], gnw[2], gnb[2], cw1[2], cb1[2], U, P);
    edge_kernel<256, 8><<<N_NODES, 512, 0, stream>>>(U, P, knn, w2t2, cb2[2], y, s1l[2], s2l[2]);

    // Layer 4: fused node+edge (persistent, internal grid barrier)
    fused_kernel<256><<<FBLK, 512, 0, stream>>>(y, pos, s1l[2], s2l[2], gnms[3], gnw[3], gnb[3],
                                                cw1[3], cb1[3], U, P, knn, w2t3, cb2[3], y,
                                                s1l[3], s2l[3], bar);

    // Layer 5: fused node+edge
    fused_kernel<512><<<FBLK, 512, 0, stream>>>(y, pos, s1l[3], s2l[3], gnms[4], gnw[4], gnb[4],
                                                cw1[4], cb1[4], U, P, knn, w2t4, cb2[4], y,
                                                s1l[4], s2l[4], bar);

    // gn6 (stats from L5 edge atomics) fused into classifier
    cls_kernel<<<N_NODES / 16, 256, 0, stream>>>(y, s1l[4], s2l[4], gnms[5], gnw[5], gnb[5], clsw, clsb, out);
}

// Round 20
// 720.726 us; speedup vs baseline: 1.8393x; 1.8393x over previous
//
#include <hip/hip_runtime.h>
#include <stdint.h>

#define N_NODES 4096
#define NGRAPH 8
#define NPTS 512
#define KNN 64
#define EPSN 1e-5f

typedef _Float16 f16x8 __attribute__((ext_vector_type(8)));
typedef float f32x4 __attribute__((ext_vector_type(4)));
typedef unsigned long long u64;

__device__ __forceinline__ unsigned short f2h(float f) {
    _Float16 h = (_Float16)f;   // RNE, v_cvt_f16_f32
    union { _Float16 h; unsigned short u; } cv; cv.h = h;
    return cv.u;
}

// 16-col blocked layout (for 16x16x32 MFMA)
__device__ __forceinline__ void w2cv(const float* __restrict__ src, unsigned short* __restrict__ dst,
                                     int off, int lg2c) {
    int C = 1 << lg2c;
    int k = off >> lg2c, n = off & (C - 1);
    int d = ((n >> 4) * (C / 32) + (k >> 5)) * 512 + ((k >> 3) & 3) * 128 + (n & 15) * 8 + (k & 7);
    dst[d] = f2h(src[off]);
}

// ---------------- setup: w2 conversions + stat-zero + gn1 stats + kNN, one dispatch ----------------
__global__ __launch_bounds__(64) void setup_kernel(const float* __restrict__ pos, int* __restrict__ knn_out,
                                                   const float* __restrict__ wa, const float* __restrict__ wb,
                                                   const float* __restrict__ wc, const float* __restrict__ wd,
                                                   const float* __restrict__ we,
                                                   unsigned short* __restrict__ oa, unsigned short* __restrict__ ob,
                                                   unsigned short* __restrict__ oc, unsigned short* __restrict__ od,
                                                   unsigned short* __restrict__ oe,
                                                   float* __restrict__ statz,
                                                   const float* __restrict__ ms1, const float* __restrict__ gw1,
                                                   float* __restrict__ Aa, float* __restrict__ Sa) {
#pragma clang fp contract(off)
    __shared__ float px[NPTS], py[NPTS], pz[NPTS];
    __shared__ u64 keys[NPTS];
    int bid = blockIdx.x;
    int tid = threadIdx.x;   // 0..63
    int gidx = bid * 64 + tid;           // 0..262143
    for (int idx = gidx; idx < 40960; idx += 262144) statz[idx] = 0.f;
    for (int idx = gidx; idx < 610304; idx += 262144) {
        if (idx < 4096)        w2cv(wa, oa, idx, 6);
        else if (idx < 20480)  w2cv(wb, ob, idx - 4096, 7);
        else if (idx < 86016)  w2cv(wc, oc, idx - 20480, 8);
        else if (idx < 348160) w2cv(wd, od, idx - 86016, 9);
        else                   w2cv(we, oe, idx - 348160, 9);
    }
    if (bid < 24) {   // gn1 stats: 24 (graph,channel) wave-jobs
        int g = bid / 3, ch = bid - g * 3;
        float s1 = 0.f, s2 = 0.f;
        for (int n = tid; n < NPTS; n += 64) {
            float v = pos[(g * NPTS + n) * 3 + ch];
            s1 += v; s2 += v * v;
        }
        #pragma unroll
        for (int off = 32; off; off >>= 1) { s1 += __shfl_xor(s1, off); s2 += __shfl_xor(s2, off); }
        if (tid == 0) {
            float mean = s1 * (1.f / NPTS);
            float av = mean * ms1[ch];
            float var = s2 * (1.f / NPTS) - 2.f * av * mean + av * av;
            Aa[g * 3 + ch] = av;
            Sa[g * 3 + ch] = gw1[ch] / sqrtf(var + EPSN);
        }
    }
    // ---- kNN: 1-wave bitonic sort of this dst point's 512 keys ----
    int b = bid >> 9;
    int il = bid & (NPTS - 1);
    for (int n = tid; n < NPTS; n += 64) {
        int base = (b * NPTS + n) * 3;
        px[n] = pos[base]; py[n] = pos[base + 1]; pz[n] = pos[base + 2];
    }
    __syncthreads();
    float xi = px[il], yi = py[il], zi = pz[il];
    for (int n = tid; n < NPTS; n += 64) {
        float dx = px[n] - xi, dy = py[n] - yi, dz = pz[n] - zi;
        float d2 = dx * dx;
        d2 = d2 + dy * dy;
        d2 = d2 + dz * dz;
        keys[n] = (((u64)__float_as_uint(d2)) << 32) | (unsigned)n;
    }
    __syncthreads();
    for (int k2 = 2; k2 <= NPTS; k2 <<= 1) {
        for (int j = k2 >> 1; j > 0; j >>= 1) {
            #pragma unroll 4
            for (int p = 0; p < 4; ++p) {
                int pid = tid + p * 64;
                int t = ((pid & ~(j - 1)) << 1) | (pid & (j - 1));
                int ixj = t | j;
                u64 a = keys[t], c = keys[ixj];
                bool up = ((t & k2) == 0);
                if ((a > c) == up) { keys[t] = c; keys[ixj] = a; }
            }
            __syncthreads();
        }
    }
    int j0 = (int)(keys[tid] & 0xffffffffu);
    knn_out[(size_t)(b * NPTS + il) * KNN + tid] = b * NPTS + j0;
}

// ---------------- Per-node MLP1 with fused GraphNorm apply on input ----------------
template<int CIN, int C, int RELU, int RAW>
__global__ __launch_bounds__(C) void node_kernel(const float* __restrict__ y, const float* __restrict__ pos,
                                                 const float* __restrict__ p1, const float* __restrict__ p2,
                                                 const float* __restrict__ ms, const float* __restrict__ gw,
                                                 const float* __restrict__ bnp,
                                                 const float* __restrict__ w1, const float* __restrict__ b1,
                                                 float* __restrict__ U, float* __restrict__ P) {
    constexpr int ROWS = 16;
    constexpr int KC = 64;
    constexpr int LDH = KC + 4;
    __shared__ float hs[ROWS][LDH];   // 4352 B
    __shared__ float As_[CIN > 0 ? CIN : 1], Ss_[CIN > 0 ? CIN : 1];
    const int c = threadIdx.x;
    const int n0 = blockIdx.x * ROWS;
    const int b = n0 >> 9;            // all 16 rows in one graph
    if (RAW) {
        for (int ch = c; ch < CIN; ch += C) {
            float s1 = p1[b * CIN + ch], s2 = p2[b * CIN + ch];
            float mean = s1 * (1.f / NPTS);
            float a = mean * ms[ch];
            float var = s2 * (1.f / NPTS) - 2.f * a * mean + a * a;
            As_[ch] = a;
            Ss_[ch] = gw[ch] / sqrtf(var + EPSN);
        }
    }
    float acc[ROWS];
    #pragma unroll
    for (int r = 0; r < ROWS; ++r) acc[r] = 0.f;
    constexpr int NCHUNK = (CIN + KC - 1) / KC;
    #pragma unroll 1
    for (int s = 0; s < NCHUNK; ++s) {
        const int k0 = s * KC;
        const int kc = (CIN - k0 < KC) ? (CIN - k0) : KC;
        __syncthreads();
        for (int idx = c; idx < ROWS * kc; idx += C) {
            int r = idx / kc, k = idx - r * kc;
            int ch = k0 + k;
            float a = RAW ? As_[ch] : p1[b * CIN + ch];
            float sf = RAW ? Ss_[ch] : p2[b * CIN + ch];
            float v = (y[(size_t)(n0 + r) * CIN + ch] - a) * sf + bnp[ch];
            if (RELU) v = fmaxf(v, 0.f);
            hs[r][k] = v;
        }
        __syncthreads();
        int k = 0;
        for (; k + 4 <= kc; k += 4) {
            float w0 = w1[(size_t)(k0 + k) * C + c];
            float w1v = w1[(size_t)(k0 + k + 1) * C + c];
            float w2v = w1[(size_t)(k0 + k + 2) * C + c];
            float w3v = w1[(size_t)(k0 + k + 3) * C + c];
            #pragma unroll
            for (int r = 0; r < ROWS; ++r) {
                f32x4 hv = *(const f32x4*)&hs[r][k];
                acc[r] = fmaf(hv[0], w0, acc[r]);
                acc[r] = fmaf(hv[1], w1v, acc[r]);
                acc[r] = fmaf(hv[2], w2v, acc[r]);
                acc[r] = fmaf(hv[3], w3v, acc[r]);
            }
        }
        for (; k < kc; ++k) {
            float wv = w1[(size_t)(k0 + k) * C + c];
            #pragma unroll
            for (int r = 0; r < ROWS; ++r)
                acc[r] = fmaf(hs[r][k], wv, acc[r]);
        }
    }
    float pacc[ROWS];
    #pragma unroll
    for (int r = 0; r < ROWS; ++r) pacc[r] = 0.f;
    #pragma unroll
    for (int e = 0; e < 3; ++e) {
        float wv = w1[(size_t)(CIN + e) * C + c];
        #pragma unroll
        for (int r = 0; r < ROWS; ++r)
            pacc[r] = fmaf(pos[(n0 + r) * 3 + e], wv, pacc[r]);
    }
    float bv = b1[c];
    #pragma unroll
    for (int r = 0; r < ROWS; ++r) {
        U[(size_t)(n0 + r) * C + c] = acc[r] + pacc[r] + bv;
        P[(size_t)(n0 + r) * C + c] = pacc[r];
    }
}

// ---------------- Edge MLP2 + scatter-max (R9 shape; P-row staged in LDS) + atomic stats ----------------
template<int C, int W>
__global__ __launch_bounds__(W * 64, 4) void edge_kernel(const float* __restrict__ U, const float* __restrict__ P,
                                                         const int* __restrict__ knn, const unsigned short* __restrict__ w2t,
                                                         const float* __restrict__ b2, float* __restrict__ Y,
                                                         float* __restrict__ sum1, float* __restrict__ sum2) {
    constexpr int NCT = C / (W * 16);    // col tiles per wave
    constexpr int EPT = 32 / W;          // staging cols per thread (8 or 4)
    constexpr int S = C / 32;            // barrier iterations (one k32 each)
    constexpr int LD = 40;               // LDS row stride (halves)
    __shared__ unsigned short Tb[2][64 * LD];
    __shared__ int jn[64];
    __shared__ float Pr[C];              // block-uniform dst-row of P
    const int bid = blockIdx.x;
    const int i = ((bid & 7) << 9) | (bid >> 3);   // XCD = bid%8 = graph(i): gather stays in one L2
    const int tid = threadIdx.x;
    const int wave = tid >> 6, lane = tid & 63, m = lane & 15, quad = lane >> 4;
    const int cw = wave * (NCT * 16);
    if (tid < 64) jn[tid] = knn[(size_t)i * KNN + tid];
    for (int idx = tid; idx < C; idx += W * 64) Pr[idx] = P[(size_t)i * C + idx];
    f32x4 acc[4][NCT];
    f32x4 zero = {0.f, 0.f, 0.f, 0.f};
    #pragma unroll
    for (int rt = 0; rt < 4; ++rt)
        #pragma unroll
        for (int ct = 0; ct < NCT; ++ct)
            acc[rt][ct] = zero;
    const int rr = tid / W;              // staging row 0..63
    const int c0 = (tid % W) * EPT;      // staging col base within k32 window
    __syncthreads();                     // jn + Pr visible
    const float* upr = U + (size_t)jn[rr] * C + c0;
    float4 uf[EPT / 4];
    #pragma unroll
    for (int g = 0; g < EPT / 4; ++g)
        uf[g] = *(const float4*)(upr + g * 4);
    #pragma unroll 2
    for (int s = 0; s < S; ++s) {
        unsigned short* tb = Tb[s & 1];
        if constexpr (EPT == 8) {
            float4 p0 = *(const float4*)&Pr[s * 32 + c0];
            float4 p1 = *(const float4*)&Pr[s * 32 + c0 + 4];
            uint4 pk;
            pk.x = (unsigned)f2h(fmaxf(uf[0].x - p0.x, 0.f)) | ((unsigned)f2h(fmaxf(uf[0].y - p0.y, 0.f)) << 16);
            pk.y = (unsigned)f2h(fmaxf(uf[0].z - p0.z, 0.f)) | ((unsigned)f2h(fmaxf(uf[0].w - p0.w, 0.f)) << 16);
            pk.z = (unsigned)f2h(fmaxf(uf[1].x - p1.x, 0.f)) | ((unsigned)f2h(fmaxf(uf[1].y - p1.y, 0.f)) << 16);
            pk.w = (unsigned)f2h(fmaxf(uf[1].z - p1.z, 0.f)) | ((unsigned)f2h(fmaxf(uf[1].w - p1.w, 0.f)) << 16);
            *(uint4*)&tb[rr * LD + c0] = pk;
        } else {
            float4 p0 = *(const float4*)&Pr[s * 32 + c0];
            uint2 pk;
            pk.x = (unsigned)f2h(fmaxf(uf[0].x - p0.x, 0.f)) | ((unsigned)f2h(fmaxf(uf[0].y - p0.y, 0.f)) << 16);
            pk.y = (unsigned)f2h(fmaxf(uf[0].z - p0.z, 0.f)) | ((unsigned)f2h(fmaxf(uf[0].w - p0.w, 0.f)) << 16);
            *(uint2*)&tb[rr * LD + c0] = pk;
        }
        if (s + 1 < S) {                 // A-prefetch next k32 window (U only; P is LDS-resident)
            #pragma unroll
            for (int g = 0; g < EPT / 4; ++g)
                uf[g] = *(const float4*)(upr + (s + 1) * 32 + g * 4);
        }
        __syncthreads();
        f16x8 a[4];
        #pragma unroll
        for (int rt = 0; rt < 4; ++rt)
            a[rt] = *(const f16x8*)&tb[(rt * 16 + m) * LD + quad * 8];
        #pragma unroll
        for (int ct = 0; ct < NCT; ++ct) {
            const f16x8 bb = *(const f16x8*)(w2t +
                (size_t)(((cw >> 4) + ct) * S + s) * 512 + quad * 128 + m * 8);
            #pragma unroll
            for (int rt = 0; rt < 4; ++rt)
                acc[rt][ct] = __builtin_amdgcn_mfma_f32_16x16x32_f16(a[rt], bb, acc[rt][ct], 0, 0, 0);
        }
    }
    const int gb = i >> 9;
    #pragma unroll
    for (int ct = 0; ct < NCT; ++ct) {
        float vmax = -3.4e38f;
        #pragma unroll
        for (int rt = 0; rt < 4; ++rt) {
            vmax = fmaxf(vmax, acc[rt][ct][0]);
            vmax = fmaxf(vmax, acc[rt][ct][1]);
            vmax = fmaxf(vmax, acc[rt][ct][2]);
            vmax = fmaxf(vmax, acc[rt][ct][3]);
        }
        vmax = fmaxf(vmax, __shfl_xor(vmax, 16));
        vmax = fmaxf(vmax, __shfl_xor(vmax, 32));
        if (quad == 0) {
            int col = cw + ct * 16 + m;
            float val = vmax + b2[col];
            Y[(size_t)i * C + col] = val;
            atomicAdd(&sum1[gb * C + col], val);
            atomicAdd(&sum2[gb * C + col], val * val);
        }
    }
}

// ---------------- Classifier with fused gn6 (stats from atomic sums) ----------------
__global__ __launch_bounds__(256) void cls_kernel(const float* __restrict__ y, const float* __restrict__ sum1,
                                                  const float* __restrict__ sum2, const float* __restrict__ ms,
                                                  const float* __restrict__ gw, const float* __restrict__ gnb,
                                                  const float* __restrict__ w, const float* __restrict__ bias,
                                                  float* __restrict__ out) {
    __shared__ float wl[512 * 14];      // 28672 B
    __shared__ _Float16 hn[16][520];    // 16640 B (pad 8 -> 2-way LDS aliasing only)
    __shared__ float As[512], Ss[512];  // 4096 B
    int tid = threadIdx.x;
    int n0 = blockIdx.x * 16;
    int b = n0 >> 9;
    for (int ch = tid; ch < 512; ch += 256) {
        float s1 = sum1[b * 512 + ch], s2 = sum2[b * 512 + ch];
        float mean = s1 * (1.f / NPTS);
        float a = mean * ms[ch];
        float var = s2 * (1.f / NPTS) - 2.f * a * mean + a * a;
        As[ch] = a;
        Ss[ch] = gw[ch] / sqrtf(var + EPSN);
    }
    for (int idx = tid; idx < 512 * 14; idx += 256) wl[idx] = w[idx];
    __syncthreads();
    for (int idx = tid; idx < 16 * 512; idx += 256) {
        int r = idx >> 9, k = idx & 511;
        float v = (y[(size_t)(n0 + r) * 512 + k] - As[k]) * Ss[k] + gnb[k];
        hn[r][k] = (_Float16)fmaxf(v, 0.f);
    }
    __syncthreads();
    if (tid < 224) {
        int nl = tid / 14, c = tid - nl * 14;
        float acc = bias[c];
        for (int k = 0; k < 512; ++k)
            acc += (float)hn[nl][k] * wl[k * 14 + c];
        out[(size_t)(n0 + nl) * 14 + c] = acc;
    }
}

extern "C" void kernel_launch(void* const* d_in, const int* in_sizes, int n_in,
                              void* d_out, int out_size, void* d_ws, size_t ws_size,
                              hipStream_t stream) {
    const float* pos = (const float*)d_in[0];
    const float* gnw[6]; const float* gnb[6]; const float* gnms[6];
    for (int i = 0; i < 6; ++i) {
        gnw[i]  = (const float*)d_in[2 + 3 * i];
        gnb[i]  = (const float*)d_in[3 + 3 * i];
        gnms[i] = (const float*)d_in[4 + 3 * i];
    }
    const float* cw1[5]; const float* cb1[5]; const float* cw2[5]; const float* cb2[5];
    for (int i = 0; i < 5; ++i) {
        cw1[i] = (const float*)d_in[20 + 4 * i];
        cb1[i] = (const float*)d_in[21 + 4 * i];
        cw2[i] = (const float*)d_in[22 + 4 * i];
        cb2[i] = (const float*)d_in[23 + 4 * i];
    }
    const float* clsw = (const float*)d_in[40];
    const float* clsb = (const float*)d_in[41];
    float* out = (float*)d_out;

    char* ws = (char*)d_ws;
    int* knn             = (int*)(ws + 0);                 // 1 MB
    float* U             = (float*)(ws + 1048576);         // 8 MB
    float* P             = (float*)(ws + 9437184);         // 8 MB
    float* y             = (float*)(ws + 26214400);        // 8 MB
    float* Aa            = (float*)(ws + 34603008);        // 16 KB
    float* Sa            = (float*)(ws + 34619392);        // 16 KB
    unsigned short* w2t0 = (unsigned short*)(ws + 34635776);  // 8 KB
    unsigned short* w2t1 = (unsigned short*)(ws + 34643968);  // 32 KB
    unsigned short* w2t2 = (unsigned short*)(ws + 34676736);  // 128 KB
    unsigned short* w2t3 = (unsigned short*)(ws + 34807808);  // 512 KB
    unsigned short* w2t4 = (unsigned short*)(ws + 35332096);  // 512 KB
    float* acc           = (float*)(ws + 35856384);           // 160 KB: 5 x (4096+4096) floats
    float* s1l[5]; float* s2l[5];
    for (int l = 0; l < 5; ++l) { s1l[l] = acc + l * 8192; s2l[l] = s1l[l] + 4096; }

    // setup: w2 conversions + stat-zero + gn1 stats + kNN
    setup_kernel<<<N_NODES, 64, 0, stream>>>(pos, knn, cw2[0], cw2[1], cw2[2], cw2[3], cw2[4],
                                             w2t0, w2t1, w2t2, w2t3, w2t4, acc,
                                             gnms[0], gnw[0], Aa, Sa);

    // Layer 1 (gn1 apply fused into node1, no relu)
    node_kernel<3, 64, 0, 0><<<N_NODES / 16, 64, 0, stream>>>(pos, pos, Aa, Sa, gnms[0], gnw[0], gnb[0], cw1[0], cb1[0], U, P);
    edge_kernel<64, 4><<<N_NODES, 256, 0, stream>>>(U, P, knn, w2t0, cb2[0], y, s1l[0], s2l[0]);

    // Layer 2 (stats from L1 edge atomics)
    node_kernel<64, 128, 1, 1><<<N_NODES / 16, 128, 0, stream>>>(y, pos, s1l[0], s2l[0], gnms[1], gnw[1], gnb[1], cw1[1], cb1[1], U, P);
    edge_kernel<128, 8><<<N_NODES, 512, 0, stream>>>(U, P, knn, w2t1, cb2[1], y, s1l[1], s2l[1]);

    // Layer 3
    node_kernel<128, 256, 1, 1><<<N_NODES / 16, 256, 0, stream>>>(y, pos, s1l[1], s2l[1], gnms[2], gnw[2], gnb[2], cw1[2], cb1[2], U, P);
    edge_kernel<256, 8><<<N_NODES, 512, 0, stream>>>(U, P, knn, w2t2, cb2[2], y, s1l[2], s2l[2]);

    // Layer 4
    node_kernel<256, 512, 1, 1><<<N_NODES / 16, 512, 0, stream>>>(y, pos, s1l[2], s2l[2], gnms[3], gnw[3], gnb[3], cw1[3], cb1[3], U, P);
    edge_kernel<512, 8><<<N_NODES, 512, 0, stream>>>(U, P, knn, w2t3, cb2[3], y, s1l[3], s2l[3]);

    // Layer 5
    node_kernel<512, 512, 1, 1><<<N_NODES / 16, 512, 0, stream>>>(y, pos, s1l[3], s2l[3], gnms[4], gnw[4], gnb[4], cw1[4], cb1[4], U, P);
    edge_kernel<512, 8><<<N_NODES, 512, 0, stream>>>(U, P, knn, w2t4, cb2[4], y, s1l[4], s2l[4]);

    // gn6 (stats from L5 edge atomics) fused into classifier
    cls_kernel<<<N_NODES / 16, 256, 0, stream>>>(y, s1l[4], s2l[4], gnms[5], gnw[5], gnb[5], clsw, clsb, out);
}